// Round 2
// baseline (435.064 us; speedup 1.0000x reference)
//
#include <hip/hip_runtime.h>

// Conv2D_80796924772741: grouped (per-F) 3x3x1 valid correlation + int8 requantize.
// Harness protocol: int8 tensors are widened to int32 on both input AND output.
//   x: int32 [64,514,514,4], w: int32 [64,3,3,1], b: int32 [64]
//   out: int32 [64,512,512,4]  (quantized int8 values stored as int32)
// Quant: reduced_mantissa = (1305500416 + (1<<15)) >> 16 = 19920
//        total_shifts = 15 - (-7) = 22, out_zp = -5, clip [-128,127]

#define NF 64
#define HH 514
#define WW 514
#define OH 512
#define OW 512
#define RB 4   // rows per thread

__device__ __forceinline__ int quantize(int acc) {
    long long t = (long long)acc * 19920LL + (1LL << 21);
    int r = (int)(t >> 22) - 5;           // arithmetic shift, then +OUT_ZP
    r = max(-128, min(127, r));
    return r;
}

__global__ __launch_bounds__(256) void conv2d_q_kernel(const int* __restrict__ x,
                                                       const int* __restrict__ w,
                                                       const int* __restrict__ b,
                                                       int* __restrict__ out) {
    const int f   = blockIdx.z;
    const int oh0 = blockIdx.y * RB;
    const int ow  = blockIdx.x * 256 + threadIdx.x;

    // Wave-uniform weights + bias -> scalar loads.
    int wgt[9];
#pragma unroll
    for (int k = 0; k < 9; ++k) wgt[k] = w[f * 9 + k];
    const int bias = b[f];

    const int4* __restrict__ xv = reinterpret_cast<const int4*>(x);
    int4* __restrict__ ov = reinterpret_cast<int4*>(out);

    int acc[RB][4];
#pragma unroll
    for (int r = 0; r < RB; ++r)
#pragma unroll
        for (int c = 0; c < 4; ++c) acc[r][c] = bias;

    const int xbase = (f * HH + oh0) * WW + ow;   // int4-granular index

    // Stream 6 input rows; row h feeds output rows r = h-2..h (weight row m = h-r).
#pragma unroll
    for (int h = 0; h < RB + 2; ++h) {
        const int4 t0 = xv[xbase + h * WW + 0];
        const int4 t1 = xv[xbase + h * WW + 1];
        const int4 t2 = xv[xbase + h * WW + 2];
#pragma unroll
        for (int r = 0; r < RB; ++r) {
            const int m = h - r;
            if (m >= 0 && m < 3) {
                const int c0 = wgt[m * 3 + 0];
                const int c1 = wgt[m * 3 + 1];
                const int c2 = wgt[m * 3 + 2];
                acc[r][0] += t0.x * c0 + t1.x * c1 + t2.x * c2;
                acc[r][1] += t0.y * c0 + t1.y * c1 + t2.y * c2;
                acc[r][2] += t0.z * c0 + t1.z * c1 + t2.z * c2;
                acc[r][3] += t0.w * c0 + t1.w * c1 + t2.w * c2;
            }
        }
    }

    const int obase = (f * OH + oh0) * OW + ow;
#pragma unroll
    for (int r = 0; r < RB; ++r) {
        int4 o;
        o.x = quantize(acc[r][0]);
        o.y = quantize(acc[r][1]);
        o.z = quantize(acc[r][2]);
        o.w = quantize(acc[r][3]);
        ov[obase + r * OW] = o;
    }
}

extern "C" void kernel_launch(void* const* d_in, const int* in_sizes, int n_in,
                              void* d_out, int out_size, void* d_ws, size_t ws_size,
                              hipStream_t stream) {
    const int* x = (const int*)d_in[0];
    const int* w = (const int*)d_in[1];
    const int* b = (const int*)d_in[2];
    int* out = (int*)d_out;

    dim3 grid(OW / 256, OH / RB, NF);   // (2, 128, 64)
    dim3 block(256, 1, 1);
    conv2d_q_kernel<<<grid, block, 0, stream>>>(x, w, b, out);
}